// Round 4
// baseline (217.142 us; speedup 1.0000x reference)
//
#include <hip/hip_runtime.h>
#include <math.h>

// Problem constants (from reference setup_inputs)
#define B_      8
#define F_      64        // features
#define HW_     65536     // 256*256 pixels
#define NSEG    33        // N_OBJECTS + 1
#define NOBJ    32
#define FPB     8         // features per segmax block
#define SLICES  16        // pixel slices per batch
#define PIXB    (HW_ / SLICES)   // 4096 pixels per block
#define ENC_NEG_INF 0x007FFFFFu  // monotonic encoding of -inf

// Monotonic order-preserving float->uint encoding: unsigned max == float max.
__device__ __forceinline__ unsigned enc_f(float x) {
    unsigned u = __float_as_uint(x);
    return u ^ ((unsigned)((int)u >> 31) | 0x80000000u);
}
__device__ __forceinline__ float dec_f(unsigned e) {
    unsigned x = (e & 0x80000000u) ? (e ^ 0x80000000u) : ~e;
    return __uint_as_float(x);
}

// d_ws layout: float part[b][slice][NSEG][F_] = 8*16*33*64 floats = 1.08 MB.
// Every slot written unconditionally by exactly one block -> poison harmless.

// segmax: grid = 8 b * 8 fgroup * 16 slice = 1024 blocks (4/CU), 256 threads.
// Per-thread-private LDS slots acc[f_local][seg][lane]: bank = lane mod 32
// for any seg -> conflict-free; single owner per slot -> no contention.
// Update = fire-and-forget ds_max_u32 on encoded floats: 1 DS op/element,
// no dependent LDS read, no lgkmcnt stall in the stream loop.
__global__ __launch_bounds__(256) void segmax_kernel(
        const float* __restrict__ enc, const int* __restrict__ masks,
        float* __restrict__ part) {
    __shared__ unsigned acc[FPB * NSEG * 32];   // 33,792 B
    const int tid = threadIdx.x;
    const int blk = blockIdx.x;
    const int b     = blk >> 7;          // 8 fg * 16 slices = 128
    const int fg    = (blk >> 4) & 7;
    const int slice = blk & 15;

    for (int i = tid; i < FPB * NSEG * 32; i += 256) acc[i] = ENC_NEG_INF;
    __syncthreads();

    const int fl = tid >> 5;      // feature within group: 0..7
    const int l  = tid & 31;      // private lane slot
    unsigned* a = acc + fl * (NSEG * 32) + l;   // + id*32 per element

    const float4* ep = (const float4*)(enc + ((size_t)(b * F_ + fg * FPB + fl)) * HW_
                                       + slice * PIXB) + l;
    const int4*   mp = (const int4*)(masks + (size_t)b * HW_ + slice * PIXB) + l;

    #pragma unroll 8
    for (int c = 0; c < PIXB / 128; ++c) {     // 32 iters, 128 pixels each
        float4 v  = ep[c * 32];
        int4   id = mp[c * 32];
        atomicMax(a + id.x * 32, enc_f(v.x));  // ds_max_u32, no return
        atomicMax(a + id.y * 32, enc_f(v.y));
        atomicMax(a + id.z * 32, enc_f(v.z));
        atomicMax(a + id.w * 32, enc_f(v.w));
    }
    __syncthreads();

    // Reduce 32 lane-copies per (f_local, seg); decode; write slice partial.
    float* dst = part + (((size_t)b * SLICES + slice) * NSEG) * F_;
    for (int cell = tid; cell < FPB * NSEG; cell += 256) {
        int f = cell & 7, s = cell >> 3;
        const unsigned* row = acc + f * (NSEG * 32) + s * 32;
        unsigned m = ENC_NEG_INF;
        #pragma unroll
        for (int k = 0; k < 32; k += 4) {
            uint4 q = *(const uint4*)(row + k);
            unsigned m1 = q.x > q.y ? q.x : q.y;
            unsigned m2 = q.z > q.w ? q.z : q.w;
            unsigned m3 = m1 > m2 ? m1 : m2;
            m = m > m3 ? m : m3;
        }
        dst[s * F_ + fg * FPB + f] = dec_f(m);
    }
}

// mlp: grid = 8 b * 4 i-tiles = 32 blocks. Reduces the 16 slice partials,
// writes vectors, then h = A_i + B_j + b1, out = sigmoid(h@W2 + b2),
// connections[b][c][j][i] = out[i][j][c]. All weights staged in LDS.
__global__ __launch_bounds__(256) void mlp_kernel(
        const float* __restrict__ part,
        const float* __restrict__ W1, const float* __restrict__ b1,
        const float* __restrict__ W2, const float* __restrict__ b2,
        float* __restrict__ out_vec, float* __restrict__ out_conn) {
    const int b   = blockIdx.x >> 2;
    const int it  = blockIdx.x & 3;          // i-tile: i = it*8 .. it*8+7
    const int tid = threadIdx.x;
    __shared__ float v[NOBJ * 65];           // [obj][f], pad 65 kills i-aliasing
    __shared__ float w1s[2 * F_ * 32];       // [d][k], 16 KB
    __shared__ float w2s[32 * 4];
    __shared__ float b1s[32];
    __shared__ float Am[8 * 36];             // [i_loc][k], pad 36 (f4-aligned)
    __shared__ float Bm[NOBJ * 36];

    for (int i = tid; i < 2 * F_ * 32 / 4; i += 256)
        ((float4*)w1s)[i] = ((const float4*)W1)[i];
    if (tid < 32) { w2s[tid*4+0]=W2[tid*4+0]; w2s[tid*4+1]=W2[tid*4+1];
                    w2s[tid*4+2]=W2[tid*4+2]; w2s[tid*4+3]=W2[tid*4+3];
                    b1s[tid] = b1[tid]; }

    // Slice-reduce: cells (s,f) for s=1..32, f=0..63. Coalesced over f.
    for (int cell = tid; cell < NOBJ * F_; cell += 256) {
        int s = (cell >> 6) + 1, f = cell & 63;
        float m = -INFINITY;
        #pragma unroll
        for (int sl = 0; sl < SLICES; ++sl)
            m = fmaxf(m, part[(((size_t)b * SLICES + sl) * NSEG + s) * F_ + f]);
        v[(s - 1) * 65 + f] = m;
        if (it == 0) out_vec[b * NOBJ * F_ + cell] = m;
    }
    __syncthreads();

    // 1280 length-64 dots as 320 float4-dots: d<64 -> Am (8 i_loc x 8 kg),
    // d>=64 -> Bm (32 j x 8 kg). Broadcast-friendly LDS access.
    for (int d = tid; d < 320; d += 256) {
        int kg, obj, half;
        if (d < 64) { half = 0; obj = it * 8 + (d >> 3); kg = d & 7; }
        else        { half = 1; obj = (d - 64) >> 3;     kg = d & 7; }
        const float* vv = v + obj * 65;
        const float* w  = w1s + half * (F_ * 32) + kg * 4;
        float4 s4 = {0.f, 0.f, 0.f, 0.f};
        #pragma unroll
        for (int f = 0; f < F_; ++f) {
            float4 wf = *(const float4*)(w + f * 32);
            float x = vv[f];
            s4.x = fmaf(x, wf.x, s4.x); s4.y = fmaf(x, wf.y, s4.y);
            s4.z = fmaf(x, wf.z, s4.z); s4.w = fmaf(x, wf.w, s4.w);
        }
        if (half == 0) {
            float4 bb = *(const float4*)(b1s + kg * 4);
            s4.x += bb.x; s4.y += bb.y; s4.z += bb.z; s4.w += bb.w;
            *(float4*)(Am + (d >> 3) * 36 + kg * 4) = s4;
        } else {
            *(float4*)(Bm + obj * 36 + kg * 4) = s4;
        }
    }
    __syncthreads();

    // 256 (i,j) pairs: one per thread.
    {
        int i_loc = tid >> 5, j = tid & 31;
        float o0 = b2[0], o1 = b2[1], o2 = b2[2], o3 = b2[3];
        #pragma unroll
        for (int kg = 0; kg < 8; ++kg) {
            float4 ha = *(const float4*)(Am + i_loc * 36 + kg * 4);
            float4 hb = *(const float4*)(Bm + j * 36 + kg * 4);
            float h0 = ha.x + hb.x, h1 = ha.y + hb.y;
            float h2 = ha.z + hb.z, h3 = ha.w + hb.w;
            const float* w2 = w2s + kg * 16;
            o0 = fmaf(h0, w2[0],  fmaf(h1, w2[4],  fmaf(h2, w2[8],  fmaf(h3, w2[12], o0))));
            o1 = fmaf(h0, w2[1],  fmaf(h1, w2[5],  fmaf(h2, w2[9],  fmaf(h3, w2[13], o1))));
            o2 = fmaf(h0, w2[2],  fmaf(h1, w2[6],  fmaf(h2, w2[10], fmaf(h3, w2[14], o2))));
            o3 = fmaf(h0, w2[3],  fmaf(h1, w2[7],  fmaf(h2, w2[11], fmaf(h3, w2[15], o3))));
        }
        float* oc = out_conn + (size_t)b * 4 * NOBJ * NOBJ + j * NOBJ + (it * 8 + i_loc);
        oc[0 * NOBJ * NOBJ] = 1.f / (1.f + expf(-o0));
        oc[1 * NOBJ * NOBJ] = 1.f / (1.f + expf(-o1));
        oc[2 * NOBJ * NOBJ] = 1.f / (1.f + expf(-o2));
        oc[3 * NOBJ * NOBJ] = 1.f / (1.f + expf(-o3));
    }
}

extern "C" void kernel_launch(void* const* d_in, const int* in_sizes, int n_in,
                              void* d_out, int out_size, void* d_ws, size_t ws_size,
                              hipStream_t stream) {
    const float* enc   = (const float*)d_in[0];
    const int*   masks = (const int*)  d_in[1];
    const float* W1    = (const float*)d_in[2];
    const float* b1    = (const float*)d_in[3];
    const float* W2    = (const float*)d_in[4];
    const float* b2    = (const float*)d_in[5];

    float* out_vec  = (float*)d_out;                 // 8*32*64 = 16384 floats
    float* out_conn = out_vec + B_ * NOBJ * F_;      // 8*4*32*32 = 32768 floats
    float* part     = (float*)d_ws;                  // 1.08 MB slice partials

    segmax_kernel<<<B_ * (F_ / FPB) * SLICES, 256, 0, stream>>>(enc, masks, part);
    mlp_kernel<<<B_ * 4, 256, 0, stream>>>(part, W1, b1, W2, b2, out_vec, out_conn);
}